// Round 5
// baseline (2265.182 us; speedup 1.0000x reference)
//
#include <hip/hip_runtime.h>
#include <hip/hip_bf16.h>
#include <math.h>

#define DIM   384
#define HEADS 6
#define HD    64
#define NB    16      // batch
#define HW    56
#define N1    (HW*HW)   // 3136
#define H2    28
#define N2    (H2*H2)   // 784
#define H3    14
#define N3    (H3*H3)   // 196
#define NT    49        // global tokens
#define HIDN  1536
#define SCL   0.125f
#define PH    30        // padded height for conv input
#define PW    36        // padded width

typedef short s8v __attribute__((ext_vector_type(8)));   // 8 bf16 (4 VGPRs)
typedef float f4v __attribute__((ext_vector_type(4)));   // MFMA accumulator

__device__ __forceinline__ short f2b(float f){           // f32 -> bf16 RNE
    unsigned u = __builtin_bit_cast(unsigned, f);
    unsigned r = (u + 0x7FFFu + ((u >> 16) & 1u)) >> 16;
    return (short)r;
}
__device__ __forceinline__ float b2f(short s){
    return __builtin_bit_cast(float, ((unsigned)(unsigned short)s) << 16);
}
__device__ __forceinline__ unsigned pk2(float a, float b){
    return (unsigned)(unsigned short)f2b(a) | ((unsigned)(unsigned short)f2b(b) << 16);
}

// ---------------- conv weight [O,I,3,3] -> bf16 [co][tap][ci]
__global__ void k_wconv(const float* __restrict__ w, short* __restrict__ wtb, int total)
{
    int idx = blockIdx.x * 256 + threadIdx.x;
    if (idx >= total) return;
    int ci  = idx % DIM;
    int tap = (idx / DIM) % 9;
    int co  = idx / (9*DIM);
    wtb[idx] = f2b(w[((size_t)co*DIM + ci)*9 + tap]);
}

// ---------------- tiled transpose + cvt: src f32 [R][C] -> dst bf16 [C][R]
__global__ __launch_bounds__(256)
void k_tcvt(const float* __restrict__ src, short* __restrict__ dst, int R, int C, int rt)
{
    int tile = blockIdx.x;
    int tr = tile % rt, tc = tile / rt;
    int r0 = tr*32, c0 = tc*32;
    int tx = threadIdx.x & 31, ty = threadIdx.x >> 5;
    __shared__ float t[32][33];
    #pragma unroll
    for (int j = 0; j < 4; ++j)
        t[ty + j*8][tx] = src[(size_t)(r0 + ty + j*8)*C + c0 + tx];
    __syncthreads();
    #pragma unroll
    for (int j = 0; j < 4; ++j)
        dst[(size_t)(c0 + ty + j*8)*R + r0 + tx] = f2b(t[tx][ty + j*8]);
}

// ---------------- depthwise 3x3 conv + bias + LN(1e-6) -> bf16; 4-pixel quad/block
__global__ __launch_bounds__(384)
void k_dwln(const float* __restrict__ x, const float* __restrict__ dww,
            const float* __restrict__ dwb, const float* __restrict__ g,
            const float* __restrict__ bt, short* __restrict__ out)
{
    const int bx = blockIdx.x;            // b*(HW*14) + h*14 + wq
    const int wq = bx % 14;
    const int h  = (bx / 14) % HW;
    const int b  = bx / (14*HW);
    const int w0 = wq * 4;
    const int c  = threadIdx.x;
    float wv[9];
    #pragma unroll
    for (int t = 0; t < 9; ++t) wv[t] = dww[c*9 + t];
    float vin[3][6];
    #pragma unroll
    for (int rr = 0; rr < 3; ++rr){
        int ih = h + rr - 1;
        #pragma unroll
        for (int cc = 0; cc < 6; ++cc){
            int iw = w0 + cc - 1;
            vin[rr][cc] = (ih >= 0 && ih < HW && iw >= 0 && iw < HW)
                        ? x[((size_t)(b*N1 + ih*HW + iw))*DIM + c] : 0.f;
        }
    }
    float bb = dwb[c];
    float acc[4];
    #pragma unroll
    for (int p = 0; p < 4; ++p){
        float a = bb;
        #pragma unroll
        for (int kh = 0; kh < 3; ++kh)
            #pragma unroll
            for (int kw = 0; kw < 3; ++kw)
                a += vin[kh][p + kw] * wv[kh*3 + kw];
        acc[p] = a;
    }
    float s[4], q[4];
    #pragma unroll
    for (int p = 0; p < 4; ++p){ s[p] = acc[p]; q[p] = acc[p]*acc[p]; }
    #pragma unroll
    for (int off = 32; off; off >>= 1){
        #pragma unroll
        for (int p = 0; p < 4; ++p){
            s[p] += __shfl_down(s[p], off);
            q[p] += __shfl_down(q[p], off);
        }
    }
    __shared__ float rs[6][4], rq[6][4];
    int lane = threadIdx.x & 63, wv_ = threadIdx.x >> 6;
    if (!lane){
        #pragma unroll
        for (int p = 0; p < 4; ++p){ rs[wv_][p] = s[p]; rq[wv_][p] = q[p]; }
    }
    __syncthreads();
    float gc = g[c], bc = bt[c];
    #pragma unroll
    for (int p = 0; p < 4; ++p){
        float ts = 0.f, tq = 0.f;
        #pragma unroll
        for (int i = 0; i < 6; ++i){ ts += rs[i][p]; tq += rq[i][p]; }
        float mean = ts * (1.f/DIM);
        float var  = tq * (1.f/DIM) - mean*mean;
        float rstd = rsqrtf(var + 1e-6f);
        out[((size_t)(b*N1 + h*HW + w0 + p))*DIM + c] = f2b((acc[p] - mean)*rstd*gc + bc);
    }
}

// ---------------- fused MFMA MLP v4: out = x + gamma*( gelu(xb@W1+b1)@W2 + b2 )
// wave = 16 tokens, X in regs; swapped phase-1; wave-private Hs; W2 dbuf LDS.
#define W2P 40   // padded pitch (shorts): 80B rows -> 16B-aligned, <=2-way banks
__global__ __launch_bounds__(256)
void k_mlp_mfma(const short* __restrict__ xb, const float* __restrict__ x,
                const short* __restrict__ w1t, const float* __restrict__ b1,
                const short* __restrict__ w2t, const float* __restrict__ b2,
                const float* __restrict__ gamma, float* __restrict__ out)
{
    __shared__ short W2c[2*384*W2P];     // 61440 B (double-buffered)
    __shared__ short Hs[4*16*W2P];       // 5120 B, wave-private slabs
    const int tid = threadIdx.x;
    const int w  = tid >> 6;
    const int l  = tid & 63;
    const int lr = l & 15;
    const int lg = l >> 4;
    const int tw = blockIdx.x*64 + w*16;          // wave's 16 tokens
    short* hsw = &Hs[w*16*W2P];

    // X into registers (exact B-fragment layout), once
    s8v xr[12];
    #pragma unroll
    for (int ks = 0; ks < 12; ++ks)
        xr[ks] = *(const s8v*)&xb[(size_t)(tw + lr)*DIM + ks*32 + lg*8];

    f4v acc[24];
    #pragma unroll
    for (int n = 0; n < 24; ++n) acc[n] = (f4v){0.f,0.f,0.f,0.f};

    // stage pair 0 into buf 0
    s8v sreg[6];
    #pragma unroll
    for (int c = 0; c < 6; ++c){
        int f = tid + c*256, n = f >> 2, k = (f & 3)*8;
        sreg[c] = *(const s8v*)&w2t[(size_t)n*HIDN + k];
    }
    #pragma unroll
    for (int c = 0; c < 6; ++c){
        int f = tid + c*256, n = f >> 2, k = (f & 3)*8;
        *(s8v*)&W2c[n*W2P + k] = sreg[c];
    }
    __syncthreads();

    for (int hp = 0; hp < 48; ++hp){
        const int hc0 = hp*32;
        // issue next pair's global loads early (hide under compute)
        if (hp < 47){
            #pragma unroll
            for (int c = 0; c < 6; ++c){
                int f = tid + c*256, n = f >> 2, k = (f & 3)*8;
                sreg[c] = *(const s8v*)&w2t[(size_t)n*HIDN + hc0 + 32 + k];
            }
        }
        // ---- phase 1: H^T tile (hidden x token), W1 frags gathered via L1
        #pragma unroll
        for (int ht = 0; ht < 2; ++ht){
            f4v a1 = (f4v){0.f,0.f,0.f,0.f};
            #pragma unroll
            for (int ks = 0; ks < 12; ++ks){
                s8v av = *(const s8v*)&w1t[(size_t)(hc0 + ht*16 + lr)*DIM + ks*32 + lg*8];
                a1 = __builtin_amdgcn_mfma_f32_16x16x32_bf16(av, xr[ks], a1, 0, 0, 0);
            }
            float4 bb = *(const float4*)&b1[hc0 + ht*16 + lg*4];
            float h0 = a1[0] + bb.x, h1 = a1[1] + bb.y;
            float h2 = a1[2] + bb.z, h3 = a1[3] + bb.w;
            h0 = h0 / (1.f + __expf(-1.702f*h0));
            h1 = h1 / (1.f + __expf(-1.702f*h1));
            h2 = h2 / (1.f + __expf(-1.702f*h2));
            h3 = h3 / (1.f + __expf(-1.702f*h3));
            *(unsigned*)&hsw[lr*W2P + ht*16 + lg*4]     = pk2(h0, h1);
            *(unsigned*)&hsw[lr*W2P + ht*16 + lg*4 + 2] = pk2(h2, h3);
        }
        // ---- phase 2: acc += H @ W2pair (K=32), A-frag straight from Hs
        const short* cur = &W2c[(hp & 1)*384*W2P];
        s8v ha = *(const s8v*)&hsw[lr*W2P + lg*8];
        #pragma unroll
        for (int n = 0; n < 24; ++n){
            s8v bv = *(const s8v*)&cur[(n*16 + lr)*W2P + lg*8];
            acc[n] = __builtin_amdgcn_mfma_f32_16x16x32_bf16(ha, bv, acc[n], 0, 0, 0);
        }
        // ---- write next pair into the other buffer
        if (hp < 47){
            short* nxt = &W2c[((hp + 1) & 1)*384*W2P];
            #pragma unroll
            for (int c = 0; c < 6; ++c){
                int f = tid + c*256, n = f >> 2, k = (f & 3)*8;
                *(s8v*)&nxt[n*W2P + k] = sreg[c];
            }
        }
        __syncthreads();
    }
    // ---- epilogue: residual + layer scale
    #pragma unroll
    for (int n = 0; n < 24; ++n){
        const int col = n*16 + lr;
        const float gm = gamma[col], bb2 = b2[col];
        #pragma unroll
        for (int r = 0; r < 4; ++r){
            size_t idx = (size_t)(tw + lg*4 + r)*DIM + col;
            out[idx] = x[idx] + gm * (acc[n][r] + bb2);
        }
    }
}

// ---------------- MFMA GEMM: C[M, colblks*384] = A[M,384] @ WT^T (+bias)
#define XS_STR 392
__global__ __launch_bounds__(256)
void k_gemm_mfma(const float* __restrict__ A, const short* __restrict__ WT,
                 const float* __restrict__ bias, float* __restrict__ outf,
                 short* __restrict__ outb, int ldo)
{
    __shared__ short As[64*XS_STR];
    const int t0   = blockIdx.x * 64;
    const int col0 = blockIdx.y * 384;
    const int tid = threadIdx.x;
    const int w   = tid >> 6;
    const int l   = tid & 63;
    const int lr  = l & 15;
    const int lg  = l >> 4;

    #pragma unroll
    for (int it = 0; it < 12; ++it){
        int i = tid + it*256;
        int row = i / 48, c8 = (i % 48) * 8;
        const float4* p = (const float4*)&A[(size_t)(t0+row)*DIM + c8];
        float4 u = p[0], v = p[1];
        s8v pk;
        pk[0]=f2b(u.x); pk[1]=f2b(u.y); pk[2]=f2b(u.z); pk[3]=f2b(u.w);
        pk[4]=f2b(v.x); pk[5]=f2b(v.y); pk[6]=f2b(v.z); pk[7]=f2b(v.w);
        *(s8v*)&As[row*XS_STR + c8] = pk;
    }
    __syncthreads();

    f4v a2[4][6];
    #pragma unroll
    for (int m = 0; m < 4; ++m)
        #pragma unroll
        for (int n = 0; n < 6; ++n) a2[m][n] = (f4v){0.f,0.f,0.f,0.f};

    #pragma unroll 4
    for (int ks = 0; ks < 12; ++ks){
        const int k0 = ks*32 + lg*8;
        s8v av[4];
        #pragma unroll
        for (int m = 0; m < 4; ++m)
            av[m] = *(const s8v*)&As[(m*16 + lr)*XS_STR + k0];
        #pragma unroll
        for (int n = 0; n < 6; ++n){
            s8v bv = *(const s8v*)&WT[(size_t)(col0 + w*96 + n*16 + lr)*DIM + k0];
            #pragma unroll
            for (int m = 0; m < 4; ++m)
                a2[m][n] = __builtin_amdgcn_mfma_f32_16x16x32_bf16(av[m], bv, a2[m][n], 0, 0, 0);
        }
    }
    #pragma unroll
    for (int n = 0; n < 6; ++n){
        const int col = col0 + w*96 + n*16 + lr;
        const float bb = bias ? bias[col] : 0.f;
        #pragma unroll
        for (int m = 0; m < 4; ++m){
            #pragma unroll
            for (int r = 0; r < 4; ++r){
                size_t idx = (size_t)(t0 + m*16 + lg*4 + r)*ldo + col;
                float v = a2[m][n][r] + bb;
                if (outb) outb[idx] = f2b(v);
                else      outf[idx] = v;
            }
        }
    }
}

// ---------------- avgpool2 (56->28) + cvt bf16 + write into zero-padded buffer
__global__ __launch_bounds__(384)
void k_poolpad(const float* __restrict__ in, short* __restrict__ pad)
{
    int pix = blockIdx.x;                 // b*N2 + oh*28 + ow
    int b = pix / N2, r = pix % N2;
    int oh = r / H2, ow = r % H2;
    int c = threadIdx.x;
    size_t base = ((size_t)b * HW * HW + (size_t)(2*oh)*HW + 2*ow) * DIM;
    const float* p00 = &in[base];
    const float* p01 = p00 + DIM;
    const float* p10 = p00 + (size_t)HW*DIM;
    const float* p11 = p10 + DIM;
    float v = 0.25f * (p00[c] + p01[c] + p10[c] + p11[c]);
    pad[(((size_t)b*PH + oh + 1)*PW + ow + 1)*DIM + c] = f2b(v);
}

// ---------------- conv 3x3 (384->384, no bias) as implicit MFMA GEMM
__global__ __launch_bounds__(256)
void k_conv_mfma(const short* __restrict__ pad, const short* __restrict__ wtb,
                 float* __restrict__ out)
{
    const int bx = blockIdx.x;            // b*28 + oh
    const int oh = bx % H2;
    const int b  = bx / H2;
    const int tid = threadIdx.x;
    const int w   = tid >> 6;
    const int l   = tid & 63;
    const int lr  = l & 15;
    const int lg  = l >> 4;

    f4v acc[2][6];
    #pragma unroll
    for (int m = 0; m < 2; ++m)
        #pragma unroll
        for (int n = 0; n < 6; ++n) acc[m][n] = (f4v){0.f,0.f,0.f,0.f};

    #pragma unroll
    for (int kh = 0; kh < 3; ++kh){
        #pragma unroll
        for (int kw = 0; kw < 3; ++kw){
            const short* Ab = pad + (((size_t)b*PH + oh + kh)*PW + kw)*DIM;
            const short* Bb = wtb + (size_t)(kh*3 + kw)*DIM;
            #pragma unroll 3
            for (int ks = 0; ks < 12; ++ks){
                const int k0 = ks*32 + lg*8;
                s8v a0 = *(const s8v*)&Ab[(size_t)(lr     )*DIM + k0];
                s8v a1 = *(const s8v*)&Ab[(size_t)(lr + 16)*DIM + k0];
                #pragma unroll
                for (int n = 0; n < 6; ++n){
                    s8v bv = *(const s8v*)&Bb[(size_t)(w*96 + n*16 + lr)*(9*DIM) + k0];
                    acc[0][n] = __builtin_amdgcn_mfma_f32_16x16x32_bf16(a0, bv, acc[0][n], 0, 0, 0);
                    acc[1][n] = __builtin_amdgcn_mfma_f32_16x16x32_bf16(a1, bv, acc[1][n], 0, 0, 0);
                }
            }
        }
    }
    #pragma unroll
    for (int n = 0; n < 6; ++n){
        const int col = w*96 + n*16 + lr;
        #pragma unroll
        for (int m = 0; m < 2; ++m){
            #pragma unroll
            for (int r = 0; r < 4; ++r){
                int px = m*16 + lg*4 + r;
                if (px < H2)
                    out[((size_t)(b*N2 + oh*H2 + px))*DIM + col] = acc[m][n][r];
            }
        }
    }
}

// ---------------- LN(1e-5) + ReLU + avgpool2 (28->14)
__global__ __launch_bounds__(384)
void k_lnpool(const float* __restrict__ conv, const float* __restrict__ g,
              const float* __restrict__ bt, float* __restrict__ out)
{
    int pix = blockIdx.x;                 // b*N3 + oh*14 + ow
    int b = pix / N3, r = pix % N3;
    int oh = r / H3, ow = r % H3;
    int c = threadIdx.x;
    float v[4];
    #pragma unroll
    for (int j = 0; j < 4; ++j){
        int ih = 2*oh + (j >> 1), iw = 2*ow + (j & 1);
        v[j] = conv[((size_t)(b*N2 + ih*H2 + iw))*DIM + c];
    }
    float s[4], q[4];
    #pragma unroll
    for (int j = 0; j < 4; ++j){ s[j] = v[j]; q[j] = v[j]*v[j]; }
    #pragma unroll
    for (int off = 32; off; off >>= 1){
        #pragma unroll
        for (int j = 0; j < 4; ++j){
            s[j] += __shfl_down(s[j], off);
            q[j] += __shfl_down(q[j], off);
        }
    }
    __shared__ float rs[6][4], rq[6][4];
    int lane = threadIdx.x & 63, wv = threadIdx.x >> 6;
    if (!lane){
        #pragma unroll
        for (int j = 0; j < 4; ++j){ rs[wv][j] = s[j]; rq[wv][j] = q[j]; }
    }
    __syncthreads();
    float gc = g[c], bc = bt[c];
    float o = 0.f;
    #pragma unroll
    for (int j = 0; j < 4; ++j){
        float ts = 0.f, tq = 0.f;
        #pragma unroll
        for (int i = 0; i < 6; ++i){ ts += rs[i][j]; tq += rq[i][j]; }
        float mean = ts * (1.f/DIM);
        float var  = tq * (1.f/DIM) - mean*mean;
        float rstd = rsqrtf(var + 1e-5f);
        o += fmaxf((v[j] - mean) * rstd * gc + bc, 0.f);
    }
    out[(size_t)pix*DIM + c] = 0.25f * o;
}

// ---------------- f32 GEMM (small shapes)
__global__ __launch_bounds__(256)
void k_gemm(const float* __restrict__ A, int lda,
            const float* __restrict__ W, const float* __restrict__ bias,
            float* __restrict__ out, int ldo, int K, int nb)
{
    int bx = blockIdx.x;
    int m0 = (bx / nb) * 16;
    int cb = (bx % nb) * 64;
    int tid = threadIdx.x;
    int r  = tid >> 4;
    int cg = tid & 15;
    int N  = nb * 64;
    __shared__ float As[16*32];
    __shared__ float Ws[32*64];
    float acc[4] = {0,0,0,0};
    for (int k0 = 0; k0 < K; k0 += 32){
        int e = tid;
        #pragma unroll
        for (int i = 0; i < 2; ++i){
            int rr = e >> 5, kk = e & 31;
            As[rr*32 + kk] = A[(size_t)(m0+rr)*lda + k0 + kk];
            e += 256;
        }
        int f = tid;
        #pragma unroll
        for (int i = 0; i < 8; ++i){
            int kr = f >> 6, cc = f & 63;
            Ws[kr*64 + cc] = W[(size_t)(k0+kr)*N + cb + cc];
            f += 256;
        }
        __syncthreads();
        #pragma unroll 8
        for (int kk = 0; kk < 32; ++kk){
            float a = As[r*32 + kk];
            #pragma unroll
            for (int j = 0; j < 4; ++j)
                acc[j] += a * Ws[kk*64 + cg*4 + j];
        }
        __syncthreads();
    }
    #pragma unroll
    for (int j = 0; j < 4; ++j){
        int c = cb + cg*4 + j;
        float v = acc[j] + (bias ? bias[c] : 0.f);
        out[(size_t)(m0 + r)*ldo + c] = v;
    }
}

// ---------------- generic MHA: 32-query tile per block (float4 K/V loads)
__global__ __launch_bounds__(256)
void k_attn(const float* __restrict__ qp, const short* __restrict__ qb16, int ldq,
            const float* __restrict__ kp, const float* __restrict__ vp, int ldkv,
            float* __restrict__ op, int ldo,
            const float* __restrict__ addp,
            int Nq, int Nk, int qtiles, int spad)
{
    int bx = blockIdx.x;
    int qt = bx % qtiles;
    int h  = (bx / qtiles) % HEADS;
    int b  = bx / (qtiles * HEADS);
    int q0 = qt * 32;
    const float* kb = kp + (size_t)b*Nk*ldkv + h*HD;
    const float* vb = vp + (size_t)b*Nk*ldkv + h*HD;
    int tid = threadIdx.x;
    __shared__ float Q[32*HD];
    __shared__ float S[32*196];
    for (int e = tid; e < 32*HD; e += 256){
        int r = e >> 6, d = e & 63;
        float qv = 0.f;
        if (q0 + r < Nq){
            size_t qi = (size_t)(b*Nq + q0 + r)*ldq + h*HD + d;
            qv = (qb16 ? b2f(qb16[qi]) : qp[qi]) * SCL;
        }
        Q[e] = qv;
    }
    __syncthreads();
    for (int s = tid; s < 32*Nk; s += 256){
        int qi = s / Nk, ki = s - qi*Nk;
        if (q0 + qi < Nq){
            const float4* q4 = (const float4*)&Q[qi*HD];
            const float4* k4 = (const float4*)&kb[(size_t)ki*ldkv];
            float dot = 0.f;
            #pragma unroll
            for (int d4 = 0; d4 < 16; ++d4){
                float4 a = q4[d4], bq = k4[d4];
                dot += a.x*bq.x + a.y*bq.y + a.z*bq.z + a.w*bq.w;
            }
            S[qi*spad + ki] = dot;
        }
    }
    __syncthreads();
    {
        int r = tid >> 3, sub = tid & 7;
        if (q0 + r < Nq){
            float m = -1e30f;
            for (int k = sub; k < Nk; k += 8) m = fmaxf(m, S[r*spad + k]);
            #pragma unroll
            for (int off = 4; off; off >>= 1) m = fmaxf(m, __shfl_xor(m, off, 8));
            float sum = 0.f;
            for (int k = sub; k < Nk; k += 8){
                float e = __expf(S[r*spad + k] - m);
                S[r*spad + k] = e;
                sum += e;
            }
            #pragma unroll
            for (int off = 4; off; off >>= 1) sum += __shfl_xor(sum, off, 8);
            float inv = 1.f / sum;
            for (int k = sub; k < Nk; k += 8) S[r*spad + k] *= inv;
        }
    }
    __syncthreads();
    {
        int qi = tid >> 3, d0 = (tid & 7) * 8;
        if (q0 + qi < Nq){
            float o[8] = {0,0,0,0,0,0,0,0};
            for (int k = 0; k < Nk; ++k){
                float p = S[qi*spad + k];
                const float* vr = &vb[(size_t)k*ldkv + d0];
                float4 v0 = *(const float4*)&vr[0];
                float4 v1 = *(const float4*)&vr[4];
                o[0] += p*v0.x; o[1] += p*v0.y; o[2] += p*v0.z; o[3] += p*v0.w;
                o[4] += p*v1.x; o[5] += p*v1.y; o[6] += p*v1.z; o[7] += p*v1.w;
            }
            size_t ob = (size_t)(b*Nq + q0 + qi)*ldo + h*HD + d0;
            #pragma unroll
            for (int j = 0; j < 8; ++j){
                float v = o[j];
                if (addp) v += addp[ob + j];
                op[ob + j] = v;
            }
        }
    }
}

extern "C" void kernel_launch(void* const* d_in, const int* in_sizes, int n_in,
                              void* d_out, int out_size, void* d_ws, size_t ws_size,
                              hipStream_t stream)
{
    const float* x    = (const float*)d_in[0];
    const float* gtok = (const float*)d_in[1];
    const float* dww  = (const float*)d_in[2];
    const float* dwb  = (const float*)d_in[3];
    const float* lng  = (const float*)d_in[4];
    const float* lnb  = (const float*)d_in[5];
    const float* w1   = (const float*)d_in[6];
    const float* b1   = (const float*)d_in[7];
    const float* w2   = (const float*)d_in[8];
    const float* b2   = (const float*)d_in[9];
    const float* gma  = (const float*)d_in[10];
    const float* cbw  = (const float*)d_in[11];
    const float* cbg  = (const float*)d_in[12];
    const float* cbb  = (const float*)d_in[13];
    const float* qkvw = (const float*)d_in[14];
    const float* ugkv = (const float*)d_in[15];
    const float* ugq  = (const float*)d_in[16];
    const float* gbkv = (const float*)d_in[17];
    const float* gbq  = (const float*)d_in[18];
    const float* pw   = (const float*)d_in[19];
    const float* pb   = (const float*)d_in[20];

    float* ws      = (float*)d_ws;
    float* xloc    = ws;                               // [B*N1,384] f32
    float* convout = xloc    + (size_t)NB*N1*DIM;      // [B*N2,384] f32
    float* xd      = convout + (size_t)NB*N2*DIM;      // [B*N3,384]
    float* qkv     = xd      + (size_t)NB*N3*DIM;      // [B*N3,1152]
    float* xds     = qkv     + (size_t)NB*N3*3*DIM;    // [B*N3,384]
    float* k2v2    = xds     + (size_t)NB*N3*DIM;      // [B*N3,768]
    float* gq      = k2v2    + (size_t)NB*N3*2*DIM;    // [B*NT,384]
    float* k3v3    = gq      + (size_t)NB*NT*DIM;      // [B*NT,768]
    short* xb      = (short*)(k3v3 + (size_t)NB*NT*2*DIM); // [B*N1,384] bf16
    short* pad1    = xb    + (size_t)NB*N1*DIM;        // [B,PH,PW,384] bf16
    short* wtb     = pad1  + (size_t)NB*PH*PW*DIM;     // [384][9][384] bf16
    short* w1t     = wtb   + (size_t)DIM*9*DIM;        // [1536][384]
    short* w2t     = w1t   + (size_t)HIDN*DIM;         // [384][1536]
    short* qkvwT   = w2t   + (size_t)DIM*HIDN;         // [1152][384]
    short* ugkvT   = qkvwT + (size_t)3*DIM*DIM;        // [768][384]
    short* gbqT    = ugkvT + (size_t)2*DIM*DIM;        // [384][384]
    short* pwT     = gbqT  + (size_t)DIM*DIM;          // [384][384]
    short* q3b     = xb;   // overlay: xb dead after k_mlp_mfma

    float* xout = (float*)d_out;
    float* gt   = xout + (size_t)NB*N1*DIM;

    // weight prep
    k_wconv<<<(DIM*9*DIM + 255)/256, 256, 0, stream>>>(cbw, wtb, DIM*9*DIM);
    k_tcvt<<<(DIM/32)*(HIDN/32), 256, 0, stream>>>(w1, w1t, DIM, HIDN, DIM/32);
    k_tcvt<<<(HIDN/32)*(DIM/32), 256, 0, stream>>>(w2, w2t, HIDN, DIM, HIDN/32);
    k_tcvt<<<(DIM/32)*(3*DIM/32), 256, 0, stream>>>(qkvw, qkvwT, DIM, 3*DIM, DIM/32);
    k_tcvt<<<(DIM/32)*(2*DIM/32), 256, 0, stream>>>(ugkv, ugkvT, DIM, 2*DIM, DIM/32);
    k_tcvt<<<(DIM/32)*(DIM/32), 256, 0, stream>>>(gbq, gbqT, DIM, DIM, DIM/32);
    k_tcvt<<<(DIM/32)*(DIM/32), 256, 0, stream>>>(pw, pwT, DIM, DIM, DIM/32);
    // ConvEncoder
    k_dwln<<<NB*HW*14, 384, 0, stream>>>(x, dww, dwb, lng, lnb, xb);
    k_mlp_mfma<<<NB*N1/64, 256, 0, stream>>>(xb, x, w1t, b1, w2t, b2, gma, xloc);
    // down_1 (pool fused with pad+cvt) -> conv(MFMA) -> LN+ReLU+down_2
    hipMemsetAsync(pad1, 0, (size_t)NB*PH*PW*DIM*sizeof(short), stream);
    k_poolpad<<<NB*N2, 384, 0, stream>>>(xloc, pad1);
    k_conv_mfma<<<NB*H2, 256, 0, stream>>>(pad1, wtb, convout);
    k_lnpool<<<NB*N3, 384, 0, stream>>>(convout, cbg, cbb, xd);
    // global aggregation (MHSA over 196 tokens)
    k_gemm_mfma<<<dim3(NB*N3/64, 3), 256, 0, stream>>>(xd, qkvwT, nullptr, qkv, nullptr, 3*DIM);
    k_attn<<<NB*HEADS*7, 256, 0, stream>>>(qkv, nullptr, 3*DIM, qkv+DIM, qkv+2*DIM, 3*DIM, xds, DIM, nullptr, N3, N3, 7, 196);
    // global token update
    k_gemm_mfma<<<dim3(NB*N3/64, 2), 256, 0, stream>>>(xds, ugkvT, nullptr, k2v2, nullptr, 2*DIM);
    k_gemm<<<(NB*NT/16)*(DIM/64), 256, 0, stream>>>(gtok, DIM, ugq, nullptr, gq, DIM, DIM, DIM/64);
    k_attn<<<NB*HEADS*2, 256, 0, stream>>>(gq, nullptr, DIM, k2v2, k2v2+DIM, 2*DIM, gt, DIM, nullptr, NT, N3, 2, 196);
    // global broadcast
    k_gemm<<<(NB*NT/16)*(2*DIM/64), 256, 0, stream>>>(gt, DIM, gbkv, nullptr, k3v3, 2*DIM, DIM, 2*DIM/64);
    k_gemm_mfma<<<dim3(NB*N1/64, 1), 256, 0, stream>>>(x, gbqT, nullptr, nullptr, q3b, DIM);
    k_attn<<<NB*HEADS*98, 256, 0, stream>>>(nullptr, q3b, DIM, k3v3, k3v3+DIM, 2*DIM, xloc, DIM, xloc, N1, NT, 98, 56);
    // final projection
    k_gemm_mfma<<<dim3(NB*N1/64, 1), 256, 0, stream>>>(xloc, pwT, pb, xout, nullptr, DIM);
}